// Round 12
// baseline (766.662 us; speedup 1.0000x reference)
//
#include <hip/hip_runtime.h>

#define NB 64
#define NS 2048
#define ND 64
#define KSTEP 64
#define NIT (NS / KSTEP)  // 32

typedef __bf16 bf16x8 __attribute__((ext_vector_type(8)));
typedef float f32x4 __attribute__((ext_vector_type(4)));
typedef float f32x16 __attribute__((ext_vector_type(16)));
typedef unsigned int u32;
typedef u32 u32x2 __attribute__((ext_vector_type(2)));
typedef u32 u32x4 __attribute__((ext_vector_type(4)));
typedef unsigned short u16;
typedef u16 u16x8 __attribute__((ext_vector_type(8)));

#define C2F 0.18033688011112042f  // log2(e)/8

__device__ __forceinline__ float fexp2(float x) { return exp2f(x); }
__device__ __forceinline__ float flog2(float x) { return log2f(x); }

// Barrier without the vmcnt(0) drain __syncthreads imposes (r8: -55us).
#define TILE_BARRIER()                                   \
  do {                                                   \
    asm volatile("s_waitcnt lgkmcnt(0)" ::: "memory");   \
    __builtin_amdgcn_s_barrier();                        \
    asm volatile("" ::: "memory");                       \
  } while (0)

__device__ __forceinline__ u16 f2bs(float x) {
  __bf16 h = (__bf16)x;
  return __builtin_bit_cast(u16, h);
}

__device__ __forceinline__ bf16x8 cvt8(f32x4 a, f32x4 b) {
  bf16x8 r;
  r[0] = (__bf16)a[0]; r[1] = (__bf16)a[1]; r[2] = (__bf16)a[2]; r[3] = (__bf16)a[3];
  r[4] = (__bf16)b[0]; r[5] = (__bf16)b[1]; r[6] = (__bf16)b[2]; r[7] = (__bf16)b[3];
  return r;
}

// position<->k permutation: swap bits 2 and 3 (self-inverse, within 16-k windows)
__device__ __host__ __forceinline__ int swap23(int p) {
  return (p & ~12) | ((p & 4) << 1) | ((p & 8) >> 1);
}

// ---------- prep 1: K fp32 -> bf16 ----------
__global__ __launch_bounds__(256) void prep_cast_k(const float* __restrict__ K,
                                                   u16* __restrict__ Kbf) {
  const size_t i = ((size_t)blockIdx.x * 256 + threadIdx.x) * 8;
  f32x4 a = __builtin_nontemporal_load((const f32x4*)(K + i));
  f32x4 b = __builtin_nontemporal_load((const f32x4*)(K + i + 4));
  *(bf16x8*)(Kbf + i) = cvt8(a, b);
}

// ---------- prep 2: V fp32 [b][k][d] -> bf16 V^T [b][d][perm k] ----------
// Position p holds k = swap23(p) within each 16-k window, so the 32x32x16
// PV A-operand slot (h,s) [reads pos 8h+s] = V[k = 4h+(s&3)+8*(s>>2)],
// exactly matching the W B-operand's D-register k layout.
__global__ __launch_bounds__(256) void prep_transp_v(const float* __restrict__ V,
                                                     u16* __restrict__ VT) {
  __shared__ __attribute__((aligned(16))) u16 T[64][72];
  const int b = blockIdx.x >> 5, kt = blockIdx.x & 31;
  const float* src = V + ((size_t)b * NS + kt * 64) * ND;
  {
    const int k = threadIdx.x >> 2, d0 = (threadIdx.x & 3) * 16;
    const float* p = src + (size_t)k * ND + d0;
    f32x4 a0 = __builtin_nontemporal_load((const f32x4*)p);
    f32x4 a1 = __builtin_nontemporal_load((const f32x4*)(p + 4));
    f32x4 a2 = __builtin_nontemporal_load((const f32x4*)(p + 8));
    f32x4 a3 = __builtin_nontemporal_load((const f32x4*)(p + 12));
    *(bf16x8*)&T[k][d0]     = cvt8(a0, a1);
    *(bf16x8*)&T[k][d0 + 8] = cvt8(a2, a3);
  }
  __syncthreads();
  const int d = threadIdx.x >> 2, k0 = (threadIdx.x & 3) * 16;
  u16x8 r0, r1;
#pragma unroll
  for (int j = 0; j < 8; ++j) {
    r0[j] = T[swap23(k0 + j)][d];
    r1[j] = T[swap23(k0 + 8 + j)][d];
  }
  u16* dst = VT + ((size_t)b * ND + d) * NS + kt * 64 + k0;
  *(u16x8*)dst = r0;
  *(u16x8*)(dst + 8) = r1;
}

// ---------- prep 3: int mask -> bit mask ----------
__global__ __launch_bounds__(256) void prep_pack_mask(const int* __restrict__ M,
                                                      unsigned long long* __restrict__ Mb) {
  const size_t i = (size_t)blockIdx.x * 256 + threadIdx.x;
  const unsigned long long bal = __ballot(M[i] != 0);
  if ((threadIdx.x & 63) == 0) Mb[i >> 6] = bal;
}

// r12: 32x32x16 MFMA version of the r11 skeleton. 256 thr / 4 waves:
// (wq = w&1 -> 32-q subtile, kt = w>>1 -> k-half). 64 q-rows/block, 2048
// blocks, 4 blocks/CU (LDS 37.4KB, VGPR cap 128) = 2 even generations.
// Each ds_read_b128 now feeds a 32-q MFMA -> LDS read traffic per element
// halves vs 16x16x32 (the r11 critical-path resource, ~120us/CU).
// mfma_f32_32x32x16_bf16 facts (HW-verified r3): A[row=l&31][k=8h+s],
// B[k=8h+s][col=l&31], D[col=l&31][row=(reg&3)+8*(reg>>2)+4h].
// QK^T role-swapped (A=K,B=Q): lane owns W[q=l&31][k=4h+(reg&3)+8*(reg>>2)]
// -> f32x4 wts stores; W feeds PV's B straight from registers; V^T stored
// with swap23 permutation makes PV's A slot map agree (verified r3 end-to-end).
template <bool PRE>
__global__ __launch_bounds__(256, 4) void DotProductAttention_22436909154804_kernel(
    const float* __restrict__ Q, const float* __restrict__ K,
    const float* __restrict__ V, const int* __restrict__ M,
    const u16* __restrict__ Kbf, const u16* __restrict__ VTbf,
    const u32* __restrict__ Mb, float* __restrict__ ctx, float* __restrict__ wts) {
  __shared__ __attribute__((aligned(16))) u16 Kt[2][64][72];  // [k][d]
  __shared__ __attribute__((aligned(16))) u16 Vt[2][64][72];  // [d][perm k]
  __shared__ float Rs[2][64];

  const int tid  = threadIdx.x;
  const int lane = tid & 63;
  const int w    = tid >> 6;   // 0..3
  const int wq   = w & 1;      // q-subtile (32 rows)
  const int kt   = w >> 1;     // k-half
  const int q    = lane & 31;
  const int h    = lane >> 5;

  // XCD swizzle: 2048 blocks = 8 XCDs x 256; consecutive vb share a batch.
  const int bid = blockIdx.x;
  const int vb  = (bid & 7) * 256 + (bid >> 3);
  const int b   = vb >> 5;
  const int qt  = vb & 31;
  const int q0w = qt * 64 + wq * 32;
  const size_t bq = (size_t)b * NS;

  // Q B-frags: qf[slab] covers d = 16*slab + 8h + s
  const float* qp = Q + (bq + q0w + q) * ND + 8 * h;
  bf16x8 qf[4];
#pragma unroll
  for (int s = 0; s < 4; ++s) {
    f32x4 qa = __builtin_nontemporal_load((const f32x4*)(qp + 16 * s));
    f32x4 qb = __builtin_nontemporal_load((const f32x4*)(qp + 16 * s + 4));
    qf[s] = cvt8(qa, qb);
  }

  const u16* Kbb = PRE ? (Kbf + bq * ND) : (const u16*)nullptr;
  const u16* VTb = PRE ? (VTbf + bq * ND) : (const u16*)nullptr;
  const float* Kb32 = K + bq * ND;
  const float* Vb32 = V + bq * ND;
  const int* Mr32  = M + (size_t)(q0w + q) * NS + kt * 32;
  const u32* MbRow = Mb + (size_t)(q0w + q) * (NS / 32);

  auto msel = [](float e, u32 mm, int idx) -> float {
    u32 keep = (u32)(((int)(mm << (31 - idx))) >> 31);
    return __uint_as_float(__float_as_uint(e) & keep);
  };

  float rs = 0.f;

  // ================ Phase 1: row sums (per k-half) ================
  if (PRE) {
    // quad-buffer overlay: KSTEP1=128; pair 0 = Kt[0..1], pair 1 = Vt[0..1]
    const int r1  = tid >> 1;        // 0..127
    const int cc1 = (tid & 1) * 32;  // 0 or 32
    u16x8 pa0, pa1, pa2, pa3;
    auto issueP1 = [&](int kb) {
      const u16* p = Kbb + (size_t)(kb + r1) * ND + cc1;
      pa0 = *(const u16x8*)p;        pa1 = *(const u16x8*)(p + 8);
      pa2 = *(const u16x8*)(p + 16); pa3 = *(const u16x8*)(p + 24);
    };
    auto writeP1 = [&](int pair) {
      u16(*dst)[72] = pair ? Vt[r1 >> 6] : Kt[r1 >> 6];
      *(u16x8*)&dst[r1 & 63][cc1]      = pa0;
      *(u16x8*)&dst[r1 & 63][cc1 + 8]  = pa1;
      *(u16x8*)&dst[r1 & 63][cc1 + 16] = pa2;
      *(u16x8*)&dst[r1 & 63][cc1 + 24] = pa3;
    };
    issueP1(0);
    writeP1(0);
    __syncthreads();
    for (int it = 0; it < 16; ++it) {
      const int pair = it & 1;
      if (it + 1 < 16) issueP1((it + 1) * 128);
      const u32x2 mv = *(const u32x2*)(MbRow + it * 4 + kt * 2);
      u16(*B)[72] = pair ? Vt[kt] : Kt[kt];  // this wave's 64-k half
#pragma unroll
      for (int win = 0; win < 2; ++win) {
        f32x16 s = {};
#pragma unroll
        for (int slab = 0; slab < 4; ++slab) {
          bf16x8 a = *(const bf16x8*)&B[win * 32 + q][16 * slab + 8 * h];
          s = __builtin_amdgcn_mfma_f32_32x32x16_bf16(a, qf[slab], s, 0, 0, 0);
        }
        const u32 mm = win ? mv.y : mv.x;
#pragma unroll
        for (int e = 0; e < 16; ++e)
          rs += msel(fexp2(s[e] * C2F), mm, 4 * h + (e & 3) + 8 * (e >> 2));
      }
      if (it + 1 < 16) writeP1((it + 1) & 1);
      TILE_BARRIER();
    }
  } else {
    // fallback: dbuf KSTEP=64, fp32 K staged in-kernel
    f32x4 kf0, kf1, kf2, kf3;
    auto issueK1 = [&](int kb) {
      const int r = tid >> 2, cc = (tid & 3) * 16;
      const float* p = Kb32 + (size_t)(kb + r) * ND + cc;
      kf0 = *(const f32x4*)p;       kf1 = *(const f32x4*)(p + 4);
      kf2 = *(const f32x4*)(p + 8); kf3 = *(const f32x4*)(p + 12);
    };
    auto writeK1 = [&](int buf) {
      const int r = tid >> 2, cc = (tid & 3) * 16;
      *(bf16x8*)&Kt[buf][r][cc]     = cvt8(kf0, kf1);
      *(bf16x8*)&Kt[buf][r][cc + 8] = cvt8(kf2, kf3);
    };
    issueK1(0);
    writeK1(0);
    __syncthreads();
    for (int it = 0; it < NIT; ++it) {
      const int cur = it & 1, kb = it * KSTEP;
      if (it + 1 < NIT) issueK1(kb + KSTEP);
      f32x16 s = {};
#pragma unroll
      for (int slab = 0; slab < 4; ++slab) {
        bf16x8 a = *(const bf16x8*)&Kt[cur][kt * 32 + q][16 * slab + 8 * h];
        s = __builtin_amdgcn_mfma_f32_32x32x16_bf16(a, qf[slab], s, 0, 0, 0);
      }
#pragma unroll
      for (int j = 0; j < 4; ++j) {
        const int4 m4 = *(const int4*)(Mr32 + kb + 8 * j + 4 * h);
        rs += (m4.x ? fexp2(s[4 * j + 0] * C2F) : 0.f)
            + (m4.y ? fexp2(s[4 * j + 1] * C2F) : 0.f)
            + (m4.z ? fexp2(s[4 * j + 2] * C2F) : 0.f)
            + (m4.w ? fexp2(s[4 * j + 3] * C2F) : 0.f);
      }
      if (it + 1 < NIT) writeK1((it + 1) & 1);
      TILE_BARRIER();
    }
  }
  rs += __shfl_xor(rs, 32);

  // ---- phase-2 staging: threads 0-127 stage K, 128-255 stage V ----
  const bool isK = tid < 128;
  const int t2   = tid & 127;
  const int row2 = t2 >> 1;        // 0..63
  const int cc2  = (t2 & 1) * 32;  // 0 or 32
  u16x8 sp0, sp1, sp2, sp3;        // PRE payloads
  f32x4 g0, g1, g2, g3, g4, g5, g6, g7;  // !PRE payloads
  const int vkp = (t2 & 31) * 2;         // !PRE V k-pair
  const int vdb = (t2 >> 5) * 16;        // !PRE V d-base
  const int vpc = swap23(vkp);           // permuted column (even)

  auto issueKV = [&](int kb) {
    if (PRE) {
      const u16* p = isK ? (Kbb + (size_t)(kb + row2) * ND + cc2)
                         : (VTb + (size_t)row2 * NS + kb + cc2);
      sp0 = *(const u16x8*)p;        sp1 = *(const u16x8*)(p + 8);
      sp2 = *(const u16x8*)(p + 16); sp3 = *(const u16x8*)(p + 24);
    } else {
      if (isK) {
        const float* p = Kb32 + (size_t)(kb + row2) * ND + cc2;
        g0 = *(const f32x4*)p;        g1 = *(const f32x4*)(p + 4);
        g2 = *(const f32x4*)(p + 8);  g3 = *(const f32x4*)(p + 12);
        g4 = *(const f32x4*)(p + 16); g5 = *(const f32x4*)(p + 20);
        g6 = *(const f32x4*)(p + 24); g7 = *(const f32x4*)(p + 28);
      } else {
        const float* p = Vb32 + (size_t)(kb + vkp) * ND + vdb;
        g0 = *(const f32x4*)p;        g1 = *(const f32x4*)(p + 4);
        g2 = *(const f32x4*)(p + 8);  g3 = *(const f32x4*)(p + 12);
        g4 = *(const f32x4*)(p + ND);      g5 = *(const f32x4*)(p + ND + 4);
        g6 = *(const f32x4*)(p + ND + 8);  g7 = *(const f32x4*)(p + ND + 12);
      }
    }
  };
  auto writeKV = [&](int buf) {
    if (PRE) {
      u16(*dst)[72] = isK ? Kt[buf] : Vt[buf];
      *(u16x8*)&dst[row2][cc2]      = sp0;
      *(u16x8*)&dst[row2][cc2 + 8]  = sp1;
      *(u16x8*)&dst[row2][cc2 + 16] = sp2;
      *(u16x8*)&dst[row2][cc2 + 24] = sp3;
    } else {
      if (isK) {
        *(bf16x8*)&Kt[buf][row2][cc2]      = cvt8(g0, g1);
        *(bf16x8*)&Kt[buf][row2][cc2 + 8]  = cvt8(g2, g3);
        *(bf16x8*)&Kt[buf][row2][cc2 + 16] = cvt8(g4, g5);
        *(bf16x8*)&Kt[buf][row2][cc2 + 24] = cvt8(g6, g7);
      } else {
        const f32x4 lo[4] = {g0, g1, g2, g3}, hi[4] = {g4, g5, g6, g7};
#pragma unroll
        for (int j = 0; j < 16; ++j)
          *(u32*)&Vt[buf][vdb + j][vpc] =
              (u32)f2bs(lo[j >> 2][j & 3]) | ((u32)f2bs(hi[j >> 2][j & 3]) << 16);
      }
    }
  };

  issueKV(0);
  if (lane < 32) Rs[kt][wq * 32 + q] = rs;
  __syncthreads();
  const float l2inv = -flog2(Rs[0][wq * 32 + q] + Rs[1][wq * 32 + q]);
  writeKV(0);
  __syncthreads();

  // ================ Phase 2: weights + PV (per k-half partials) ================
  f32x16 acc0 = {}, acc1 = {};
  float* wrow = wts + (bq + q0w + q) * NS + kt * 32;
  for (int it = 0; it < NIT; ++it) {
    const int cur = it & 1, kb = it * KSTEP;
    if (it + 1 < NIT) issueKV(kb + KSTEP);
    u32 mm = 0;
    if (PRE) mm = MbRow[it * 2 + kt];

    f32x16 s = {};
#pragma unroll
    for (int slab = 0; slab < 4; ++slab) {
      bf16x8 a = *(const bf16x8*)&Kt[cur][kt * 32 + q][16 * slab + 8 * h];
      s = __builtin_amdgcn_mfma_f32_32x32x16_bf16(a, qf[slab], s, 0, 0, 0);
    }

    u32 wpk[8];
#pragma unroll
    for (int j = 0; j < 4; ++j) {
      float w0, w1, w2, w3;
      if (PRE) {
        w0 = msel(fexp2(fmaf(s[4 * j + 0], C2F, l2inv)), mm, 4 * h + 8 * j + 0);
        w1 = msel(fexp2(fmaf(s[4 * j + 1], C2F, l2inv)), mm, 4 * h + 8 * j + 1);
        w2 = msel(fexp2(fmaf(s[4 * j + 2], C2F, l2inv)), mm, 4 * h + 8 * j + 2);
        w3 = msel(fexp2(fmaf(s[4 * j + 3], C2F, l2inv)), mm, 4 * h + 8 * j + 3);
      } else {
        const int4 m4 = *(const int4*)(Mr32 + kb + 8 * j + 4 * h);
        w0 = m4.x ? fexp2(fmaf(s[4 * j + 0], C2F, l2inv)) : 0.f;
        w1 = m4.y ? fexp2(fmaf(s[4 * j + 1], C2F, l2inv)) : 0.f;
        w2 = m4.z ? fexp2(fmaf(s[4 * j + 2], C2F, l2inv)) : 0.f;
        w3 = m4.w ? fexp2(fmaf(s[4 * j + 3], C2F, l2inv)) : 0.f;
      }
      f32x4 wv = {w0, w1, w2, w3};
      __builtin_nontemporal_store(wv, (f32x4*)(wrow + kb + 8 * j + 4 * h));
      wpk[2 * j]     = (u32)f2bs(w0) | ((u32)f2bs(w1) << 16);
      wpk[2 * j + 1] = (u32)f2bs(w2) | ((u32)f2bs(w3) << 16);
    }

    // PV: A = permuted V^T tile (slot map matches W's D layout), B = W regs
#pragma unroll
    for (int sl = 0; sl < 2; ++sl) {
      u32x4 wu = {wpk[4 * sl], wpk[4 * sl + 1], wpk[4 * sl + 2], wpk[4 * sl + 3]};
      bf16x8 wb = __builtin_bit_cast(bf16x8, wu);
      bf16x8 va0 = *(const bf16x8*)&Vt[cur][q][kt * 32 + sl * 16 + 8 * h];
      acc0 = __builtin_amdgcn_mfma_f32_32x32x16_bf16(va0, wb, acc0, 0, 0, 0);
      bf16x8 va1 = *(const bf16x8*)&Vt[cur][32 + q][kt * 32 + sl * 16 + 8 * h];
      acc1 = __builtin_amdgcn_mfma_f32_32x32x16_bf16(va1, wb, acc1, 0, 0, 0);
    }

    if (it + 1 < NIT) writeKV((it + 1) & 1);
    TILE_BARRIER();
  }

  // ---- combine ctx partials across k-halves through LDS (Kt reused) ----
  float* red = (float*)&Kt[0][0][0] + wq * (32 * 68);  // 32 q-rows x 68 f32
  if (kt == 1) {
#pragma unroll
    for (int j = 0; j < 4; ++j) {
      f32x4 v0 = {acc0[4 * j], acc0[4 * j + 1], acc0[4 * j + 2], acc0[4 * j + 3]};
      f32x4 v1 = {acc1[4 * j], acc1[4 * j + 1], acc1[4 * j + 2], acc1[4 * j + 3]};
      *(f32x4*)&red[q * 68 + 8 * j + 4 * h]      = v0;
      *(f32x4*)&red[q * 68 + 32 + 8 * j + 4 * h] = v1;
    }
  }
  __syncthreads();
  if (kt == 0) {
    float* crow = ctx + (bq + q0w + q) * ND;
#pragma unroll
    for (int j = 0; j < 4; ++j) {
      f32x4 v0 = {acc0[4 * j], acc0[4 * j + 1], acc0[4 * j + 2], acc0[4 * j + 3]};
      f32x4 v1 = {acc1[4 * j], acc1[4 * j + 1], acc1[4 * j + 2], acc1[4 * j + 3]};
      v0 += *(const f32x4*)&red[q * 68 + 8 * j + 4 * h];
      v1 += *(const f32x4*)&red[q * 68 + 32 + 8 * j + 4 * h];
      __builtin_nontemporal_store(v0, (f32x4*)(crow + 8 * j + 4 * h));
      __builtin_nontemporal_store(v1, (f32x4*)(crow + 32 + 8 * j + 4 * h));
    }
  }
}

extern "C" void kernel_launch(void* const* d_in, const int* in_sizes, int n_in,
                              void* d_out, int out_size, void* d_ws, size_t ws_size,
                              hipStream_t stream) {
  const float* Q = (const float*)d_in[0];
  const float* K = (const float*)d_in[1];
  const float* V = (const float*)d_in[2];
  const int*   M = (const int*)d_in[3];
  float* ctx = (float*)d_out;                         // [B,S,D]
  float* wts = (float*)d_out + (size_t)NB * NS * ND;  // [B,S,S]

  dim3 grid(NB * (NS / 64));  // 2048
  dim3 block(256);

  constexpr size_t KBF_B = (size_t)NB * NS * ND * 2;  // 16.78 MB
  constexpr size_t MB_B  = (size_t)NS * NS / 8;       // 0.52 MB
  u16* Kbf = (u16*)d_ws;
  u16* VTb = (u16*)((char*)d_ws + KBF_B);
  unsigned long long* Mb64 = (unsigned long long*)((char*)d_ws + 2 * KBF_B);

  if (ws_size >= 2 * KBF_B + MB_B) {
    hipLaunchKernelGGL(prep_cast_k, dim3(NB * NS * ND / 8 / 256), dim3(256), 0, stream, K, Kbf);
    hipLaunchKernelGGL(prep_transp_v, dim3(NB * (NS / 64)), dim3(256), 0, stream, V, VTb);
    hipLaunchKernelGGL(prep_pack_mask, dim3(NS * NS / 256), dim3(256), 0, stream, M, Mb64);
    hipLaunchKernelGGL(DotProductAttention_22436909154804_kernel<true>, grid, block, 0, stream,
                       Q, K, V, M, Kbf, VTb, (const u32*)Mb64, ctx, wts);
  } else {
    hipLaunchKernelGGL(DotProductAttention_22436909154804_kernel<false>, grid, block, 0, stream,
                       Q, K, V, M, (const u16*)nullptr, (const u16*)nullptr,
                       (const u32*)nullptr, ctx, wts);
  }
}

// Round 13
// 528.165 us; speedup vs baseline: 1.4516x; 1.4516x over previous
//
#include <hip/hip_runtime.h>

#define NB 64
#define NS 2048
#define ND 64
#define KSTEP 64
#define NIT (NS / KSTEP)  // 32

typedef __bf16 bf16x8 __attribute__((ext_vector_type(8)));
typedef float f32x4 __attribute__((ext_vector_type(4)));
typedef unsigned int u32;
typedef u32 u32x2 __attribute__((ext_vector_type(2)));
typedef u32 u32x4 __attribute__((ext_vector_type(4)));
typedef unsigned short u16;
typedef u16 u16x8 __attribute__((ext_vector_type(8)));

#define C2F 0.18033688011112042f  // log2(e)/8

__device__ __forceinline__ float fexp2(float x) { return exp2f(x); }
__device__ __forceinline__ float flog2(float x) { return log2f(x); }

// Barrier without the vmcnt(0) drain __syncthreads imposes (r8: -55us).
#define TILE_BARRIER()                                   \
  do {                                                   \
    asm volatile("s_waitcnt lgkmcnt(0)" ::: "memory");   \
    __builtin_amdgcn_s_barrier();                        \
    asm volatile("" ::: "memory");                       \
  } while (0)

__device__ __forceinline__ u16 f2bs(float x) {
  __bf16 h = (__bf16)x;
  return __builtin_bit_cast(u16, h);
}

__device__ __forceinline__ bf16x8 cvt8(f32x4 a, f32x4 b) {
  bf16x8 r;
  r[0] = (__bf16)a[0]; r[1] = (__bf16)a[1]; r[2] = (__bf16)a[2]; r[3] = (__bf16)a[3];
  r[4] = (__bf16)b[0]; r[5] = (__bf16)b[1]; r[6] = (__bf16)b[2]; r[7] = (__bf16)b[3];
  return r;
}

// ---------- prep 1: K fp32 -> bf16 ----------
__global__ __launch_bounds__(256) void prep_cast_k(const float* __restrict__ K,
                                                   u16* __restrict__ Kbf) {
  const size_t i = ((size_t)blockIdx.x * 256 + threadIdx.x) * 8;
  f32x4 a = __builtin_nontemporal_load((const f32x4*)(K + i));
  f32x4 b = __builtin_nontemporal_load((const f32x4*)(K + i + 4));
  *(bf16x8*)(Kbf + i) = cvt8(a, b);
}

// ---------- prep 2: V fp32 [b][k][d] -> bf16 V^T [b][d][perm k] ----------
// Position p holds k_local = 16*((p>>2)&1) + 4*((p>>3)&3) + (p&3) within
// each 32-k window, so the kernel's PV A-operand is ONE ds_read_b128.
__global__ __launch_bounds__(256) void prep_transp_v(const float* __restrict__ V,
                                                     u16* __restrict__ VT) {
  __shared__ __attribute__((aligned(16))) u16 T[64][72];
  const int b = blockIdx.x >> 5, kt = blockIdx.x & 31;
  const float* src = V + ((size_t)b * NS + kt * 64) * ND;
  {
    const int k = threadIdx.x >> 2, d0 = (threadIdx.x & 3) * 16;
    const float* p = src + (size_t)k * ND + d0;
    f32x4 a0 = __builtin_nontemporal_load((const f32x4*)p);
    f32x4 a1 = __builtin_nontemporal_load((const f32x4*)(p + 4));
    f32x4 a2 = __builtin_nontemporal_load((const f32x4*)(p + 8));
    f32x4 a3 = __builtin_nontemporal_load((const f32x4*)(p + 12));
    *(bf16x8*)&T[k][d0]     = cvt8(a0, a1);
    *(bf16x8*)&T[k][d0 + 8] = cvt8(a2, a3);
  }
  __syncthreads();
  const int d = threadIdx.x >> 2, k0 = (threadIdx.x & 3) * 16;
  u16x8 r0, r1;
#pragma unroll
  for (int j = 0; j < 8; ++j) {
    const int P0 = k0 + j, P1 = k0 + 8 + j;
    const int s0 = 32 * (P0 >> 5) + 16 * ((P0 >> 2) & 1) + 4 * ((P0 >> 3) & 3) + (P0 & 3);
    const int s1 = 32 * (P1 >> 5) + 16 * ((P1 >> 2) & 1) + 4 * ((P1 >> 3) & 3) + (P1 & 3);
    r0[j] = T[s0][d];
    r1[j] = T[s1][d];
  }
  u16* dst = VT + ((size_t)b * ND + d) * NS + kt * 64 + k0;
  *(u16x8*)dst = r0;
  *(u16x8*)(dst + 8) = r1;
}

// ---------- prep 3: int mask -> bit mask ----------
__global__ __launch_bounds__(256) void prep_pack_mask(const int* __restrict__ M,
                                                      unsigned long long* __restrict__ Mb) {
  const size_t i = (size_t)blockIdx.x * 256 + threadIdx.x;
  const unsigned long long bal = __ballot(M[i] != 0);
  if ((threadIdx.x & 63) == 0) Mb[i >> 6] = bal;
}

// K-SPLIT skeleton (r11, 336us): 512 thr / 8 waves / 64 q-rows, 2048 blocks.
// Waves (wq, kt): wq = w&3 -> 16-q-row subtile; kt = w>>2 -> k-half.
// 3 blk/CU -> 3 batches resident/XCD -> bf16 K/V L2-resident (r12: FETCH=45MB).
// r13 change: phase 1 reads K A-frags DIRECTLY from global (L2-hit bf16) --
// no LDS, no staging, ZERO barriers; waves free-run over a contiguous 1024-k
// half. Phase 2 identical to r11.
// r12 lesson: 32x32 MFMA + (256,4) -> 128-reg unified-file cap -> spill (767us).
// r10 lesson: no hand cvt_pk asm, no setprio in lockstep loops.
// mfma_f32_16x16x32_bf16 facts (HW-verified r1-2): A[row=l&15][k=8g+s],
// B[k=8g+s][col=l&15], D[m=4g+reg][n=l&15]. QK^T role-swapped (A=K,B=Q):
// lane owns W[q=c][k=16j+4g+r]; W feeds PV's B-operand from registers.
template <bool PRE>
__global__ __launch_bounds__(512, 3) void DotProductAttention_22436909154804_kernel(
    const float* __restrict__ Q, const float* __restrict__ K,
    const float* __restrict__ V, const int* __restrict__ M,
    const u16* __restrict__ Kbf, const u16* __restrict__ VTbf,
    const u32* __restrict__ Mb, float* __restrict__ ctx, float* __restrict__ wts) {
  __shared__ __attribute__((aligned(16))) u16 Kt[2][64][72];  // [k][d]
  __shared__ __attribute__((aligned(16))) u16 Vt[2][64][72];  // [d][perm k]
  __shared__ float Rs[2][64];

  const int tid  = threadIdx.x;
  const int lane = tid & 63;
  const int w    = tid >> 6;   // 0..7
  const int wq   = w & 3;      // q-subtile
  const int kt   = w >> 2;     // k-half
  const int g    = lane >> 4;  // 0..3
  const int c    = lane & 15;  // 0..15

  // XCD swizzle: 2048 blocks = 8 XCDs x 256; consecutive vb share a batch.
  const int bid = blockIdx.x;
  const int vb  = (bid & 7) * 256 + (bid >> 3);
  const int b   = vb >> 5;
  const int qt  = vb & 31;
  const int q0w = qt * 64 + wq * 16;
  const size_t bq = (size_t)b * NS;

  // Q B-frags
  const float* qp = Q + (bq + q0w + c) * ND + 8 * g;
  f32x4 qa = __builtin_nontemporal_load((const f32x4*)qp);
  f32x4 qb = __builtin_nontemporal_load((const f32x4*)(qp + 4));
  const bf16x8 qf0 = cvt8(qa, qb);
  qa = __builtin_nontemporal_load((const f32x4*)(qp + 32));
  qb = __builtin_nontemporal_load((const f32x4*)(qp + 36));
  const bf16x8 qf1 = cvt8(qa, qb);

  const u16* Kbb = PRE ? (Kbf + bq * ND) : (const u16*)nullptr;
  const u16* VTb = PRE ? (VTbf + bq * ND) : (const u16*)nullptr;
  const float* Kb32 = K + bq * ND;
  const float* Vb32 = V + bq * ND;
  const int* Mr    = M + (size_t)(q0w + c) * NS + kt * 32;
  const u32* MbRow = Mb + (size_t)(q0w + c) * (NS / 32);
  const u32* Mbr   = MbRow + kt;

  const bool isK = tid < 256;
  const int st   = tid & 255;

  auto msel = [](float e, u32 mm, int idx) -> float {
    u32 keep = (u32)(((int)(mm << (31 - idx))) >> 31);
    return __uint_as_float(__float_as_uint(e) & keep);
  };

  const f32x4 zz = {0.f, 0.f, 0.f, 0.f};
  float rs = 0.f;

  // ================ Phase 1: row sums (per k-half) ================
  if (PRE) {
    // Barrier-free: A-frags straight from global (L2-hit bf16 K).
    // Wave's half: k in [kt*1024, kt*1024+1024).
    const u16* Kh = Kbb + (size_t)kt * 1024 * ND;
    const u32* Mh = MbRow + kt * 32;
    for (int it = 0; it < 32; ++it) {
      const int k0 = it * 32;
      const u32 mm = Mh[it];
#pragma unroll
      for (int j = 0; j < 2; ++j) {
        const u16* kr = Kh + (size_t)(k0 + 16 * j + c) * ND + 8 * g;
        bf16x8 a0 = *(const bf16x8*)kr;
        bf16x8 a1 = *(const bf16x8*)(kr + 32);
        f32x4 s = __builtin_amdgcn_mfma_f32_16x16x32_bf16(a0, qf0, zz, 0, 0, 0);
        s = __builtin_amdgcn_mfma_f32_16x16x32_bf16(a1, qf1, s, 0, 0, 0);
        rs += msel(fexp2(s[0] * C2F), mm, 16 * j + 4 * g + 0)
            + msel(fexp2(s[1] * C2F), mm, 16 * j + 4 * g + 1)
            + msel(fexp2(s[2] * C2F), mm, 16 * j + 4 * g + 2)
            + msel(fexp2(s[3] * C2F), mm, 16 * j + 4 * g + 3);
      }
    }
  } else {
    // fallback: r9 staged KSTEP=64 K-only dbuf
    f32x4 kf0, kf1, kf2, kf3;
    auto issueK1 = [&](int kb) {
      if (isK) {
        const int r = st >> 2, cc = (st & 3) * 16;
        const float* p = Kb32 + (size_t)(kb + r) * ND + cc;
        kf0 = *(const f32x4*)p;       kf1 = *(const f32x4*)(p + 4);
        kf2 = *(const f32x4*)(p + 8); kf3 = *(const f32x4*)(p + 12);
      }
    };
    auto writeK1 = [&](int buf) {
      if (isK) {
        const int r = st >> 2, cc = (st & 3) * 16;
        *(bf16x8*)&Kt[buf][r][cc]     = cvt8(kf0, kf1);
        *(bf16x8*)&Kt[buf][r][cc + 8] = cvt8(kf2, kf3);
      }
    };
    issueK1(0);
    writeK1(0);
    __syncthreads();
    for (int it = 0; it < NIT; ++it) {
      const int cur = it & 1, kb = it * KSTEP;
      if (it + 1 < NIT) issueK1(kb + KSTEP);
#pragma unroll
      for (int j = 0; j < 2; ++j) {
        bf16x8 a0 = *(const bf16x8*)&Kt[cur][kt * 32 + 16 * j + c][8 * g];
        bf16x8 a1 = *(const bf16x8*)&Kt[cur][kt * 32 + 16 * j + c][32 + 8 * g];
        f32x4 s = __builtin_amdgcn_mfma_f32_16x16x32_bf16(a0, qf0, zz, 0, 0, 0);
        s = __builtin_amdgcn_mfma_f32_16x16x32_bf16(a1, qf1, s, 0, 0, 0);
        const int4 m4 = *(const int4*)(Mr + kb + 16 * j + 4 * g);
        rs += (m4.x ? fexp2(s[0] * C2F) : 0.f)
            + (m4.y ? fexp2(s[1] * C2F) : 0.f)
            + (m4.z ? fexp2(s[2] * C2F) : 0.f)
            + (m4.w ? fexp2(s[3] * C2F) : 0.f);
      }
      if (it + 1 < NIT) writeK1((it + 1) & 1);
      TILE_BARRIER();
    }
  }
  rs += __shfl_xor(rs, 16);
  rs += __shfl_xor(rs, 32);

  // ---- phase-2 staging lambdas (r9/r11) ----
  u16x8 sp0, sp1;            // PRE payloads
  f32x4 kf0, kf1, kf2, kf3;  // !PRE payloads
  auto issueKV = [&](int kb) {  // K by waves 0-3, V by waves 4-7
    if (PRE) {
      if (isK) {
        const int r = st >> 2, cc = (st & 3) * 16;
        const u16* p = Kbb + (size_t)(kb + r) * ND + cc;
        sp0 = *(const u16x8*)p; sp1 = *(const u16x8*)(p + 8);
      } else {
        const int d = st >> 2, kc = (st & 3) * 16;
        const u16* p = VTb + (size_t)d * NS + kb + kc;
        sp0 = *(const u16x8*)p; sp1 = *(const u16x8*)(p + 8);
      }
    } else {
      if (isK) {
        const int r = st >> 2, cc = (st & 3) * 16;
        const float* p = Kb32 + (size_t)(kb + r) * ND + cc;
        kf0 = *(const f32x4*)p;       kf1 = *(const f32x4*)(p + 4);
        kf2 = *(const f32x4*)(p + 8); kf3 = *(const f32x4*)(p + 12);
      } else {
        const int k = st >> 2, d0 = (st & 3) * 16;
        const float* p = Vb32 + (size_t)(kb + k) * ND + d0;
        kf0 = *(const f32x4*)p;       kf1 = *(const f32x4*)(p + 4);
        kf2 = *(const f32x4*)(p + 8); kf3 = *(const f32x4*)(p + 12);
      }
    }
  };
  auto writeKV = [&](int buf) {
    if (PRE) {
      if (isK) {
        const int r = st >> 2, cc = (st & 3) * 16;
        *(u16x8*)&Kt[buf][r][cc] = sp0; *(u16x8*)&Kt[buf][r][cc + 8] = sp1;
      } else {
        const int d = st >> 2, kc = (st & 3) * 16;
        *(u16x8*)&Vt[buf][d][kc] = sp0; *(u16x8*)&Vt[buf][d][kc + 8] = sp1;
      }
    } else {
      if (isK) {
        const int r = st >> 2, cc = (st & 3) * 16;
        *(bf16x8*)&Kt[buf][r][cc]     = cvt8(kf0, kf1);
        *(bf16x8*)&Kt[buf][r][cc + 8] = cvt8(kf2, kf3);
      } else {
        const int k = st >> 2, d0 = (st & 3) * 16;
        bf16x8 v0 = cvt8(kf0, kf1), v1 = cvt8(kf2, kf3);
#pragma unroll
        for (int j = 0; j < 8; ++j) {
          Vt[buf][d0 + j][k]     = __builtin_bit_cast(u16, v0[j]);
          Vt[buf][d0 + 8 + j][k] = __builtin_bit_cast(u16, v1[j]);
        }
      }
    }
  };

  issueKV(0);
  if (lane < 16) Rs[kt][wq * 16 + c] = rs;
  __syncthreads();
  const float l2inv = -flog2(Rs[0][wq * 16 + c] + Rs[1][wq * 16 + c]);
  writeKV(0);
  __syncthreads();

  // ================ Phase 2: weights + PV (per k-half partials) ================
  f32x4 acc[4] = {zz, zz, zz, zz};
  float* wrow = wts + (bq + q0w + c) * NS + kt * 32;
  for (int it = 0; it < NIT; ++it) {
    const int cur = it & 1, kb = it * KSTEP;
    if (it + 1 < NIT) issueKV(kb + KSTEP);
    u32 mm = 0;
    if (PRE) mm = Mbr[kb >> 5];

    u32 wpk[4];
#pragma unroll
    for (int j = 0; j < 2; ++j) {
      bf16x8 a0 = *(const bf16x8*)&Kt[cur][kt * 32 + 16 * j + c][8 * g];
      bf16x8 a1 = *(const bf16x8*)&Kt[cur][kt * 32 + 16 * j + c][32 + 8 * g];
      f32x4 s = __builtin_amdgcn_mfma_f32_16x16x32_bf16(a0, qf0, zz, 0, 0, 0);
      s = __builtin_amdgcn_mfma_f32_16x16x32_bf16(a1, qf1, s, 0, 0, 0);
      float w0, w1, w2, w3;
      if (PRE) {
        w0 = msel(fexp2(fmaf(s[0], C2F, l2inv)), mm, 16 * j + 4 * g + 0);
        w1 = msel(fexp2(fmaf(s[1], C2F, l2inv)), mm, 16 * j + 4 * g + 1);
        w2 = msel(fexp2(fmaf(s[2], C2F, l2inv)), mm, 16 * j + 4 * g + 2);
        w3 = msel(fexp2(fmaf(s[3], C2F, l2inv)), mm, 16 * j + 4 * g + 3);
      } else {
        const int4 m4 = *(const int4*)(Mr + kb + 16 * j + 4 * g);
        w0 = m4.x ? fexp2(fmaf(s[0], C2F, l2inv)) : 0.f;
        w1 = m4.y ? fexp2(fmaf(s[1], C2F, l2inv)) : 0.f;
        w2 = m4.z ? fexp2(fmaf(s[2], C2F, l2inv)) : 0.f;
        w3 = m4.w ? fexp2(fmaf(s[3], C2F, l2inv)) : 0.f;
      }
      f32x4 wv = {w0, w1, w2, w3};
      __builtin_nontemporal_store(wv, (f32x4*)(wrow + kb + 16 * j + 4 * g));
      wpk[2 * j]     = (u32)f2bs(w0) | ((u32)f2bs(w1) << 16);
      wpk[2 * j + 1] = (u32)f2bs(w2) | ((u32)f2bs(w3) << 16);
    }

    // PV partial for this wave's k-half; B = W from registers
    u32x4 wu = {wpk[0], wpk[1], wpk[2], wpk[3]};
    bf16x8 wb = __builtin_bit_cast(bf16x8, wu);
#pragma unroll
    for (int dt = 0; dt < 4; ++dt) {
      bf16x8 va;
      if (PRE) {
        va = *(const bf16x8*)&Vt[cur][dt * 16 + c][kt * 32 + 8 * g];
      } else {
        u32x2 vlo = *(const u32x2*)&Vt[cur][dt * 16 + c][kt * 32 + 4 * g];
        u32x2 vhi = *(const u32x2*)&Vt[cur][dt * 16 + c][kt * 32 + 16 + 4 * g];
        u32x4 vau = {vlo.x, vlo.y, vhi.x, vhi.y};
        va = __builtin_bit_cast(bf16x8, vau);
      }
      acc[dt] = __builtin_amdgcn_mfma_f32_16x16x32_bf16(va, wb, acc[dt], 0, 0, 0);
    }

    if (it + 1 < NIT) writeKV((it + 1) & 1);
    TILE_BARRIER();
  }

  // ---- combine ctx partials across k-halves through LDS (Kt reused) ----
  float* red = (float*)&Kt[0][0][0] + wq * 1088;  // 16 rows x 68 f32 per pair
  if (kt == 1) {
#pragma unroll
    for (int dt = 0; dt < 4; ++dt)
      *(f32x4*)&red[c * 68 + dt * 16 + 4 * g] = acc[dt];
  }
  __syncthreads();
  if (kt == 0) {
    float* crow = ctx + (bq + q0w + c) * ND;
#pragma unroll
    for (int dt = 0; dt < 4; ++dt) {
      f32x4 vv = acc[dt] + *(const f32x4*)&red[c * 68 + dt * 16 + 4 * g];
      __builtin_nontemporal_store(vv, (f32x4*)(crow + dt * 16 + 4 * g));
    }
  }
}

extern "C" void kernel_launch(void* const* d_in, const int* in_sizes, int n_in,
                              void* d_out, int out_size, void* d_ws, size_t ws_size,
                              hipStream_t stream) {
  const float* Q = (const float*)d_in[0];
  const float* K = (const float*)d_in[1];
  const float* V = (const float*)d_in[2];
  const int*   M = (const int*)d_in[3];
  float* ctx = (float*)d_out;                         // [B,S,D]
  float* wts = (float*)d_out + (size_t)NB * NS * ND;  // [B,S,S]

  dim3 grid(NB * (NS / 64));  // 2048
  dim3 block(512);

  constexpr size_t KBF_B = (size_t)NB * NS * ND * 2;  // 16.78 MB
  constexpr size_t MB_B  = (size_t)NS * NS / 8;       // 0.52 MB
  u16* Kbf = (u16*)d_ws;
  u16* VTb = (u16*)((char*)d_ws + KBF_B);
  unsigned long long* Mb64 = (unsigned long long*)((char*)d_ws + 2 * KBF_B);

  if (ws_size >= 2 * KBF_B + MB_B) {
    hipLaunchKernelGGL(prep_cast_k, dim3(NB * NS * ND / 8 / 256), dim3(256), 0, stream, K, Kbf);
    hipLaunchKernelGGL(prep_transp_v, dim3(NB * (NS / 64)), dim3(256), 0, stream, V, VTb);
    hipLaunchKernelGGL(prep_pack_mask, dim3(NS * NS / 256), dim3(256), 0, stream, M, Mb64);
    hipLaunchKernelGGL(DotProductAttention_22436909154804_kernel<true>, grid, block, 0, stream,
                       Q, K, V, M, Kbf, VTb, (const u32*)Mb64, ctx, wts);
  } else {
    hipLaunchKernelGGL(DotProductAttention_22436909154804_kernel<false>, grid, block, 0, stream,
                       Q, K, V, M, (const u16*)nullptr, (const u16*)nullptr,
                       (const u32*)nullptr, ctx, wts);
  }
}

// Round 14
// 347.242 us; speedup vs baseline: 2.2079x; 1.5210x over previous
//
#include <hip/hip_runtime.h>

#define NB 64
#define NS 2048
#define ND 64
#define KSTEP 64
#define NIT (NS / KSTEP)  // 32

typedef __bf16 bf16x8 __attribute__((ext_vector_type(8)));
typedef float f32x4 __attribute__((ext_vector_type(4)));
typedef unsigned int u32;
typedef u32 u32x2 __attribute__((ext_vector_type(2)));
typedef u32 u32x4 __attribute__((ext_vector_type(4)));
typedef unsigned short u16;
typedef u16 u16x8 __attribute__((ext_vector_type(8)));

#define C2F 0.18033688011112042f  // log2(e)/8

__device__ __forceinline__ float fexp2(float x) { return exp2f(x); }
__device__ __forceinline__ float flog2(float x) { return log2f(x); }

// Barrier without the vmcnt(0) drain __syncthreads imposes (r8: -55us).
#define TILE_BARRIER()                                   \
  do {                                                   \
    asm volatile("s_waitcnt lgkmcnt(0)" ::: "memory");   \
    __builtin_amdgcn_s_barrier();                        \
    asm volatile("" ::: "memory");                       \
  } while (0)

__device__ __forceinline__ u16 f2bs(float x) {
  __bf16 h = (__bf16)x;
  return __builtin_bit_cast(u16, h);
}

__device__ __forceinline__ bf16x8 cvt8(f32x4 a, f32x4 b) {
  bf16x8 r;
  r[0] = (__bf16)a[0]; r[1] = (__bf16)a[1]; r[2] = (__bf16)a[2]; r[3] = (__bf16)a[3];
  r[4] = (__bf16)b[0]; r[5] = (__bf16)b[1]; r[6] = (__bf16)b[2]; r[7] = (__bf16)b[3];
  return r;
}

// ---------- prep 1: K fp32 -> bf16 ----------
__global__ __launch_bounds__(256) void prep_cast_k(const float* __restrict__ K,
                                                   u16* __restrict__ Kbf) {
  const size_t i = ((size_t)blockIdx.x * 256 + threadIdx.x) * 8;
  f32x4 a = __builtin_nontemporal_load((const f32x4*)(K + i));
  f32x4 b = __builtin_nontemporal_load((const f32x4*)(K + i + 4));
  *(bf16x8*)(Kbf + i) = cvt8(a, b);
}

// ---------- prep 2: V fp32 [b][k][d] -> bf16 V^T [b][d][perm k] ----------
// Position p holds k_local = 16*((p>>2)&1) + 4*((p>>3)&3) + (p&3) within
// each 32-k window, so the kernel's PV A-operand is ONE ds_read_b128.
__global__ __launch_bounds__(256) void prep_transp_v(const float* __restrict__ V,
                                                     u16* __restrict__ VT) {
  __shared__ __attribute__((aligned(16))) u16 T[64][72];
  const int b = blockIdx.x >> 5, kt = blockIdx.x & 31;
  const float* src = V + ((size_t)b * NS + kt * 64) * ND;
  {
    const int k = threadIdx.x >> 2, d0 = (threadIdx.x & 3) * 16;
    const float* p = src + (size_t)k * ND + d0;
    f32x4 a0 = __builtin_nontemporal_load((const f32x4*)p);
    f32x4 a1 = __builtin_nontemporal_load((const f32x4*)(p + 4));
    f32x4 a2 = __builtin_nontemporal_load((const f32x4*)(p + 8));
    f32x4 a3 = __builtin_nontemporal_load((const f32x4*)(p + 12));
    *(bf16x8*)&T[k][d0]     = cvt8(a0, a1);
    *(bf16x8*)&T[k][d0 + 8] = cvt8(a2, a3);
  }
  __syncthreads();
  const int d = threadIdx.x >> 2, k0 = (threadIdx.x & 3) * 16;
  u16x8 r0, r1;
#pragma unroll
  for (int j = 0; j < 8; ++j) {
    const int P0 = k0 + j, P1 = k0 + 8 + j;
    const int s0 = 32 * (P0 >> 5) + 16 * ((P0 >> 2) & 1) + 4 * ((P0 >> 3) & 3) + (P0 & 3);
    const int s1 = 32 * (P1 >> 5) + 16 * ((P1 >> 2) & 1) + 4 * ((P1 >> 3) & 3) + (P1 & 3);
    r0[j] = T[s0][d];
    r1[j] = T[s1][d];
  }
  u16* dst = VT + ((size_t)b * ND + d) * NS + kt * 64 + k0;
  *(u16x8*)dst = r0;
  *(u16x8*)(dst + 8) = r1;
}

// ---------- prep 3: int mask -> bit mask ----------
__global__ __launch_bounds__(256) void prep_pack_mask(const int* __restrict__ M,
                                                      unsigned long long* __restrict__ Mb) {
  const size_t i = (size_t)blockIdx.x * 256 + threadIdx.x;
  const unsigned long long bal = __ballot(M[i] != 0);
  if ((threadIdx.x & 63) == 0) Mb[i >> 6] = bal;
}

// K-SPLIT skeleton (r11, 336us): 512 thr / 8 waves / 64 q-rows, 2048 blocks.
// Waves (wq, kt): wq = w&3 -> 16-q-row subtile; kt = w>>2 -> k-half.
// r14 change: (512,3) -> (512,4): 4 blk/CU = 32 waves/CU (full cap). LDS
// 37.4KB x4 = 149.6KB fits; 16x16 structure fit cap-64 before (r8).
// r13 lesson: LDS staging is DEDUPLICATION across waves -- direct-global
// A-frags quadruple L2 traffic (528us). r12 lesson: 32x32 MFMA spills at
// <=128-reg caps. r10 lesson: no hand cvt_pk asm, no lockstep setprio.
// mfma_f32_16x16x32_bf16 facts (HW-verified r1-2): A[row=l&15][k=8g+s],
// B[k=8g+s][col=l&15], D[m=4g+reg][n=l&15]. QK^T role-swapped (A=K,B=Q):
// lane owns W[q=c][k=16j+4g+r]; W feeds PV's B-operand from registers.
template <bool PRE>
__global__ __launch_bounds__(512, 4) void DotProductAttention_22436909154804_kernel(
    const float* __restrict__ Q, const float* __restrict__ K,
    const float* __restrict__ V, const int* __restrict__ M,
    const u16* __restrict__ Kbf, const u16* __restrict__ VTbf,
    const u32* __restrict__ Mb, float* __restrict__ ctx, float* __restrict__ wts) {
  __shared__ __attribute__((aligned(16))) u16 Kt[2][64][72];  // [k][d]
  __shared__ __attribute__((aligned(16))) u16 Vt[2][64][72];  // [d][perm k] (ph2); K quad-buf (ph1)
  __shared__ float Rs[2][64];

  const int tid  = threadIdx.x;
  const int lane = tid & 63;
  const int w    = tid >> 6;   // 0..7
  const int wq   = w & 3;      // q-subtile
  const int kt   = w >> 2;     // k-half
  const int g    = lane >> 4;  // 0..3
  const int c    = lane & 15;  // 0..15

  // XCD swizzle: 2048 blocks = 8 XCDs x 256; consecutive vb share a batch.
  const int bid = blockIdx.x;
  const int vb  = (bid & 7) * 256 + (bid >> 3);
  const int b   = vb >> 5;
  const int qt  = vb & 31;
  const int q0w = qt * 64 + wq * 16;
  const size_t bq = (size_t)b * NS;

  // Q B-frags
  const float* qp = Q + (bq + q0w + c) * ND + 8 * g;
  f32x4 qa = __builtin_nontemporal_load((const f32x4*)qp);
  f32x4 qb = __builtin_nontemporal_load((const f32x4*)(qp + 4));
  const bf16x8 qf0 = cvt8(qa, qb);
  qa = __builtin_nontemporal_load((const f32x4*)(qp + 32));
  qb = __builtin_nontemporal_load((const f32x4*)(qp + 36));
  const bf16x8 qf1 = cvt8(qa, qb);

  const u16* Kbb = PRE ? (Kbf + bq * ND) : (const u16*)nullptr;
  const u16* VTb = PRE ? (VTbf + bq * ND) : (const u16*)nullptr;
  const float* Kb32 = K + bq * ND;
  const float* Vb32 = V + bq * ND;
  const int* Mr   = M + (size_t)(q0w + c) * NS + kt * 32;
  const u32* MbRow = Mb + (size_t)(q0w + c) * (NS / 32);
  const u32* Mbr   = MbRow + kt;

  const bool isK = tid < 256;
  const int st   = tid & 255;

  auto msel = [](float e, u32 mm, int idx) -> float {
    u32 keep = (u32)(((int)(mm << (31 - idx))) >> 31);
    return __uint_as_float(__float_as_uint(e) & keep);
  };

  const f32x4 zz = {0.f, 0.f, 0.f, 0.f};
  float rs = 0.f;

  // ================ Phase 1: row sums (per k-half) ================
  if (PRE) {
    // KSTEP1 = 128 via quad-buffer overlay: pair 0 = (Kt[0],Kt[1]),
    // pair 1 = (Vt[0],Vt[1]); within a pair, rows 0-63 / 64-127.
    const int r1  = tid >> 2;        // 0..127
    const int cc1 = (tid & 3) * 16;  // 0,16,32,48
    u16x8 pa, pb;
    auto issueP1 = [&](int kb) {
      const u16* p = Kbb + (size_t)(kb + r1) * ND + cc1;
      pa = *(const u16x8*)p;
      pb = *(const u16x8*)(p + 8);
    };
    auto writeP1 = [&](int pair) {
      u16(*dst)[72] = pair ? Vt[r1 >> 6] : Kt[r1 >> 6];
      *(u16x8*)&dst[r1 & 63][cc1]     = pa;
      *(u16x8*)&dst[r1 & 63][cc1 + 8] = pb;
    };
    issueP1(0);
    writeP1(0);
    __syncthreads();
    for (int it = 0; it < 16; ++it) {
      const int pair = it & 1;
      if (it + 1 < 16) issueP1((it + 1) * 128);
      const u32x2 mv = *(const u32x2*)(MbRow + it * 4 + kt * 2);
      u16(*B)[72] = pair ? Vt[kt] : Kt[kt];  // this wave's 64-row k-half
#pragma unroll
      for (int j = 0; j < 4; ++j) {
        bf16x8 a0 = *(const bf16x8*)&B[16 * j + c][8 * g];
        bf16x8 a1 = *(const bf16x8*)&B[16 * j + c][32 + 8 * g];
        f32x4 s = __builtin_amdgcn_mfma_f32_16x16x32_bf16(a0, qf0, zz, 0, 0, 0);
        s = __builtin_amdgcn_mfma_f32_16x16x32_bf16(a1, qf1, s, 0, 0, 0);
        const u32 mm = (j < 2) ? mv.x : mv.y;
        const int base = 16 * (j & 1) + 4 * g;
        rs += msel(fexp2(s[0] * C2F), mm, base + 0)
            + msel(fexp2(s[1] * C2F), mm, base + 1)
            + msel(fexp2(s[2] * C2F), mm, base + 2)
            + msel(fexp2(s[3] * C2F), mm, base + 3);
      }
      if (it + 1 < 16) writeP1((it + 1) & 1);
      TILE_BARRIER();
    }
  } else {
    // fallback: r9 KSTEP=64 K-only staging
    f32x4 kf0, kf1, kf2, kf3;
    auto issueK1 = [&](int kb) {
      if (isK) {
        const int r = st >> 2, cc = (st & 3) * 16;
        const float* p = Kb32 + (size_t)(kb + r) * ND + cc;
        kf0 = *(const f32x4*)p;       kf1 = *(const f32x4*)(p + 4);
        kf2 = *(const f32x4*)(p + 8); kf3 = *(const f32x4*)(p + 12);
      }
    };
    auto writeK1 = [&](int buf) {
      if (isK) {
        const int r = st >> 2, cc = (st & 3) * 16;
        *(bf16x8*)&Kt[buf][r][cc]     = cvt8(kf0, kf1);
        *(bf16x8*)&Kt[buf][r][cc + 8] = cvt8(kf2, kf3);
      }
    };
    issueK1(0);
    writeK1(0);
    __syncthreads();
    for (int it = 0; it < NIT; ++it) {
      const int cur = it & 1, kb = it * KSTEP;
      if (it + 1 < NIT) issueK1(kb + KSTEP);
#pragma unroll
      for (int j = 0; j < 2; ++j) {
        bf16x8 a0 = *(const bf16x8*)&Kt[cur][kt * 32 + 16 * j + c][8 * g];
        bf16x8 a1 = *(const bf16x8*)&Kt[cur][kt * 32 + 16 * j + c][32 + 8 * g];
        f32x4 s = __builtin_amdgcn_mfma_f32_16x16x32_bf16(a0, qf0, zz, 0, 0, 0);
        s = __builtin_amdgcn_mfma_f32_16x16x32_bf16(a1, qf1, s, 0, 0, 0);
        const int4 m4 = *(const int4*)(Mr + kb + 16 * j + 4 * g);
        rs += (m4.x ? fexp2(s[0] * C2F) : 0.f)
            + (m4.y ? fexp2(s[1] * C2F) : 0.f)
            + (m4.z ? fexp2(s[2] * C2F) : 0.f)
            + (m4.w ? fexp2(s[3] * C2F) : 0.f);
      }
      if (it + 1 < NIT) writeK1((it + 1) & 1);
      TILE_BARRIER();
    }
  }
  rs += __shfl_xor(rs, 16);
  rs += __shfl_xor(rs, 32);

  // ---- phase-2 staging lambdas (r9) ----
  u16x8 sp0, sp1;            // PRE payloads
  f32x4 kf0, kf1, kf2, kf3;  // !PRE payloads
  auto issueKV = [&](int kb) {  // K by waves 0-3, V by waves 4-7
    if (PRE) {
      if (isK) {
        const int r = st >> 2, cc = (st & 3) * 16;
        const u16* p = Kbb + (size_t)(kb + r) * ND + cc;
        sp0 = *(const u16x8*)p; sp1 = *(const u16x8*)(p + 8);
      } else {
        const int d = st >> 2, kc = (st & 3) * 16;
        const u16* p = VTb + (size_t)d * NS + kb + kc;
        sp0 = *(const u16x8*)p; sp1 = *(const u16x8*)(p + 8);
      }
    } else {
      if (isK) {
        const int r = st >> 2, cc = (st & 3) * 16;
        const float* p = Kb32 + (size_t)(kb + r) * ND + cc;
        kf0 = *(const f32x4*)p;       kf1 = *(const f32x4*)(p + 4);
        kf2 = *(const f32x4*)(p + 8); kf3 = *(const f32x4*)(p + 12);
      } else {
        const int k = st >> 2, d0 = (st & 3) * 16;
        const float* p = Vb32 + (size_t)(kb + k) * ND + d0;
        kf0 = *(const f32x4*)p;       kf1 = *(const f32x4*)(p + 4);
        kf2 = *(const f32x4*)(p + 8); kf3 = *(const f32x4*)(p + 12);
      }
    }
  };
  auto writeKV = [&](int buf) {
    if (PRE) {
      if (isK) {
        const int r = st >> 2, cc = (st & 3) * 16;
        *(u16x8*)&Kt[buf][r][cc] = sp0; *(u16x8*)&Kt[buf][r][cc + 8] = sp1;
      } else {
        const int d = st >> 2, kc = (st & 3) * 16;
        *(u16x8*)&Vt[buf][d][kc] = sp0; *(u16x8*)&Vt[buf][d][kc + 8] = sp1;
      }
    } else {
      if (isK) {
        const int r = st >> 2, cc = (st & 3) * 16;
        *(bf16x8*)&Kt[buf][r][cc]     = cvt8(kf0, kf1);
        *(bf16x8*)&Kt[buf][r][cc + 8] = cvt8(kf2, kf3);
      } else {
        const int k = st >> 2, d0 = (st & 3) * 16;
        bf16x8 v0 = cvt8(kf0, kf1), v1 = cvt8(kf2, kf3);
#pragma unroll
        for (int j = 0; j < 8; ++j) {
          Vt[buf][d0 + j][k]     = __builtin_bit_cast(u16, v0[j]);
          Vt[buf][d0 + 8 + j][k] = __builtin_bit_cast(u16, v1[j]);
        }
      }
    }
  };

  issueKV(0);
  if (lane < 16) Rs[kt][wq * 16 + c] = rs;
  __syncthreads();
  const float l2inv = -flog2(Rs[0][wq * 16 + c] + Rs[1][wq * 16 + c]);
  writeKV(0);
  __syncthreads();

  // ================ Phase 2: weights + PV (per k-half partials) ================
  f32x4 acc[4] = {zz, zz, zz, zz};
  float* wrow = wts + (bq + q0w + c) * NS + kt * 32;
  for (int it = 0; it < NIT; ++it) {
    const int cur = it & 1, kb = it * KSTEP;
    if (it + 1 < NIT) issueKV(kb + KSTEP);
    u32 mm = 0;
    if (PRE) mm = Mbr[kb >> 5];

    u32 wpk[4];
#pragma unroll
    for (int j = 0; j < 2; ++j) {
      bf16x8 a0 = *(const bf16x8*)&Kt[cur][kt * 32 + 16 * j + c][8 * g];
      bf16x8 a1 = *(const bf16x8*)&Kt[cur][kt * 32 + 16 * j + c][32 + 8 * g];
      f32x4 s = __builtin_amdgcn_mfma_f32_16x16x32_bf16(a0, qf0, zz, 0, 0, 0);
      s = __builtin_amdgcn_mfma_f32_16x16x32_bf16(a1, qf1, s, 0, 0, 0);
      float w0, w1, w2, w3;
      if (PRE) {
        w0 = msel(fexp2(fmaf(s[0], C2F, l2inv)), mm, 16 * j + 4 * g + 0);
        w1 = msel(fexp2(fmaf(s[1], C2F, l2inv)), mm, 16 * j + 4 * g + 1);
        w2 = msel(fexp2(fmaf(s[2], C2F, l2inv)), mm, 16 * j + 4 * g + 2);
        w3 = msel(fexp2(fmaf(s[3], C2F, l2inv)), mm, 16 * j + 4 * g + 3);
      } else {
        const int4 m4 = *(const int4*)(Mr + kb + 16 * j + 4 * g);
        w0 = m4.x ? fexp2(fmaf(s[0], C2F, l2inv)) : 0.f;
        w1 = m4.y ? fexp2(fmaf(s[1], C2F, l2inv)) : 0.f;
        w2 = m4.z ? fexp2(fmaf(s[2], C2F, l2inv)) : 0.f;
        w3 = m4.w ? fexp2(fmaf(s[3], C2F, l2inv)) : 0.f;
      }
      f32x4 wv = {w0, w1, w2, w3};
      __builtin_nontemporal_store(wv, (f32x4*)(wrow + kb + 16 * j + 4 * g));
      wpk[2 * j]     = (u32)f2bs(w0) | ((u32)f2bs(w1) << 16);
      wpk[2 * j + 1] = (u32)f2bs(w2) | ((u32)f2bs(w3) << 16);
    }

    // PV partial for this wave's k-half; B = W from registers
    u32x4 wu = {wpk[0], wpk[1], wpk[2], wpk[3]};
    bf16x8 wb = __builtin_bit_cast(bf16x8, wu);
#pragma unroll
    for (int dt = 0; dt < 4; ++dt) {
      bf16x8 va;
      if (PRE) {
        va = *(const bf16x8*)&Vt[cur][dt * 16 + c][kt * 32 + 8 * g];
      } else {
        u32x2 vlo = *(const u32x2*)&Vt[cur][dt * 16 + c][kt * 32 + 4 * g];
        u32x2 vhi = *(const u32x2*)&Vt[cur][dt * 16 + c][kt * 32 + 16 + 4 * g];
        u32x4 vau = {vlo.x, vlo.y, vhi.x, vhi.y};
        va = __builtin_bit_cast(bf16x8, vau);
      }
      acc[dt] = __builtin_amdgcn_mfma_f32_16x16x32_bf16(va, wb, acc[dt], 0, 0, 0);
    }

    if (it + 1 < NIT) writeKV((it + 1) & 1);
    TILE_BARRIER();
  }

  // ---- combine ctx partials across k-halves through LDS (Kt reused) ----
  float* red = (float*)&Kt[0][0][0] + wq * 1088;  // 16 rows x 68 f32 per pair
  if (kt == 1) {
#pragma unroll
    for (int dt = 0; dt < 4; ++dt)
      *(f32x4*)&red[c * 68 + dt * 16 + 4 * g] = acc[dt];
  }
  __syncthreads();
  if (kt == 0) {
    float* crow = ctx + (bq + q0w + c) * ND;
#pragma unroll
    for (int dt = 0; dt < 4; ++dt) {
      f32x4 vv = acc[dt] + *(const f32x4*)&red[c * 68 + dt * 16 + 4 * g];
      __builtin_nontemporal_store(vv, (f32x4*)(crow + dt * 16 + 4 * g));
    }
  }
}

extern "C" void kernel_launch(void* const* d_in, const int* in_sizes, int n_in,
                              void* d_out, int out_size, void* d_ws, size_t ws_size,
                              hipStream_t stream) {
  const float* Q = (const float*)d_in[0];
  const float* K = (const float*)d_in[1];
  const float* V = (const float*)d_in[2];
  const int*   M = (const int*)d_in[3];
  float* ctx = (float*)d_out;                         // [B,S,D]
  float* wts = (float*)d_out + (size_t)NB * NS * ND;  // [B,S,S]

  dim3 grid(NB * (NS / 64));  // 2048
  dim3 block(512);

  constexpr size_t KBF_B = (size_t)NB * NS * ND * 2;     // 16.78 MB
  constexpr size_t MB_B  = (size_t)NS * NS / 8;          // 0.52 MB
  u16* Kbf = (u16*)d_ws;
  u16* VTb = (u16*)((char*)d_ws + KBF_B);
  unsigned long long* Mb64 = (unsigned long long*)((char*)d_ws + 2 * KBF_B);

  if (ws_size >= 2 * KBF_B + MB_B) {
    hipLaunchKernelGGL(prep_cast_k, dim3(NB * NS * ND / 8 / 256), dim3(256), 0, stream, K, Kbf);
    hipLaunchKernelGGL(prep_transp_v, dim3(NB * (NS / 64)), dim3(256), 0, stream, V, VTb);
    hipLaunchKernelGGL(prep_pack_mask, dim3(NS * NS / 256), dim3(256), 0, stream, M, Mb64);
    hipLaunchKernelGGL(DotProductAttention_22436909154804_kernel<true>, grid, block, 0, stream,
                       Q, K, V, M, Kbf, VTb, (const u32*)Mb64, ctx, wts);
  } else {
    hipLaunchKernelGGL(DotProductAttention_22436909154804_kernel<false>, grid, block, 0, stream,
                       Q, K, V, M, (const u16*)nullptr, (const u16*)nullptr,
                       (const u32*)nullptr, ctx, wts);
  }
}